// Round 3
// baseline (830.578 us; speedup 1.0000x reference)
//
#include <hip/hip_runtime.h>

// GCN: 2x GCNConv (5->16->32) + global mean pool + linear head.
// v3: CSR build + gather-reduce (no f32 atomics).
//   agg[i] = sum_{e:dst=i} s[src[e]] + s[i]   (self-loop folded into gather epilogue)
//   layer aggregation done in the INPUT dim (5->pad8, then 16), @W applied after.

#define BLK 256

__global__ void k_degree(const int* __restrict__ dst, int E, int* __restrict__ deg) {
    int e = blockIdx.x * blockDim.x + threadIdx.x;
    if (e < E) atomicAdd(&deg[dst[e]], 1);
}

// dinv = rsqrt(deg+1); sx8 = [dinv*x (5), 0,0,0]
__global__ void k_prep(const float* __restrict__ x, const int* __restrict__ deg,
                       float* __restrict__ dinv, float* __restrict__ sx8, int N) {
    int i = blockIdx.x * blockDim.x + threadIdx.x;
    if (i >= N) return;
    float di = rsqrtf((float)(deg[i] + 1));
    dinv[i] = di;
    float4 a, b;
    a.x = x[i * 5 + 0] * di; a.y = x[i * 5 + 1] * di;
    a.z = x[i * 5 + 2] * di; a.w = x[i * 5 + 3] * di;
    b.x = x[i * 5 + 4] * di; b.y = 0.f; b.z = 0.f; b.w = 0.f;
    float4* p = (float4*)(sx8 + i * 8);
    p[0] = a; p[1] = b;
}

// single-workgroup exclusive scan of deg -> rowptr[0..N], cursor = rowptr
__global__ void k_scan(const int* __restrict__ deg, int* __restrict__ rowptr,
                       int* __restrict__ cursor, int N) {
    __shared__ int sc[1024];
    int tid = threadIdx.x;
    int C = (N + 1023) / 1024;
    int start = tid * C, end = min(start + C, N);
    int s = 0;
    for (int p = start; p < end; ++p) s += deg[p];
    sc[tid] = s;
    __syncthreads();
    for (int off = 1; off < 1024; off <<= 1) {
        int v = (tid >= off) ? sc[tid - off] : 0;
        __syncthreads();
        sc[tid] += v;
        __syncthreads();
    }
    int run = sc[tid] - s;  // exclusive base for this chunk
    for (int p = start; p < end; ++p) {
        rowptr[p] = run;
        cursor[p] = run;
        run += deg[p];
    }
    if (tid == 1023) rowptr[N] = sc[1023];
}

// ecsr[slot] = src, slots grouped by dst
__global__ void k_fill(const int* __restrict__ src, const int* __restrict__ dst,
                       int* __restrict__ cursor, int* __restrict__ ecsr, int E) {
    int e = blockIdx.x * blockDim.x + threadIdx.x;
    if (e >= E) return;
    int d = dst[e];
    int p = atomicAdd(&cursor[d], 1);
    ecsr[p] = src[e];
}

// one wave per node; 8 subgroups x 8 features; agg8[i] = sum sx8[nbr] + sx8[i]
__global__ void k_gather8(const int* __restrict__ rowptr, const int* __restrict__ ecsr,
                          const float* __restrict__ sx8, float* __restrict__ agg8, int N) {
    int wid = (blockIdx.x * blockDim.x + threadIdx.x) >> 6;
    int lane = threadIdx.x & 63;
    if (wid >= N) return;
    int k = lane & 7, j = lane >> 3;
    int p0 = rowptr[wid], p1 = rowptr[wid + 1];
    float acc = 0.f;
    for (int p = p0 + j; p < p1; p += 8)
        acc += sx8[ecsr[p] * 8 + k];
    acc += __shfl_xor(acc, 8, 64);
    acc += __shfl_xor(acc, 16, 64);
    acc += __shfl_xor(acc, 32, 64);
    if (lane < 8) agg8[wid * 8 + k] = acc + sx8[wid * 8 + k];
}

// h1 = relu(dinv*(agg8[:5]@W1) + b1); g = dinv*h1 (16)
__global__ void k_lin1(const float* __restrict__ agg8, const float* __restrict__ dinv,
                       const float* __restrict__ W1, const float* __restrict__ b1,
                       float* __restrict__ g, int N) {
    __shared__ float sW[80], sb[16];
    if (threadIdx.x < 80) sW[threadIdx.x] = W1[threadIdx.x];
    if (threadIdx.x < 16) sb[threadIdx.x] = b1[threadIdx.x];
    __syncthreads();
    int i = blockIdx.x * blockDim.x + threadIdx.x;
    if (i >= N) return;
    float di = dinv[i];
    const float4* a4 = (const float4*)(agg8 + i * 8);
    float4 v0 = a4[0], v1 = a4[1];
    float a[5] = {v0.x, v0.y, v0.z, v0.w, v1.x};
    float4* g4 = (float4*)(g + i * 16);
#pragma unroll
    for (int q = 0; q < 4; ++q) {
        float4 v;
        float* vp = (float*)&v;
#pragma unroll
        for (int r = 0; r < 4; ++r) {
            int kk = q * 4 + r;
            float h = 0.f;
#pragma unroll
            for (int d = 0; d < 5; ++d) h = fmaf(a[d], sW[d * 16 + kk], h);
            h = fmaxf(fmaf(di, h, sb[kk]), 0.f);
            vp[r] = h * di;
        }
        g4[q] = v;
    }
}

// one wave per node; 4 subgroups x 16 features; agg16[i] = sum g[nbr] + g[i]
__global__ void k_gather16(const int* __restrict__ rowptr, const int* __restrict__ ecsr,
                           const float* __restrict__ g, float* __restrict__ agg16, int N) {
    int wid = (blockIdx.x * blockDim.x + threadIdx.x) >> 6;
    int lane = threadIdx.x & 63;
    if (wid >= N) return;
    int k = lane & 15, j = lane >> 4;
    int p0 = rowptr[wid], p1 = rowptr[wid + 1];
    float acc = 0.f;
    for (int p = p0 + j; p < p1; p += 4)
        acc += g[ecsr[p] * 16 + k];
    acc += __shfl_xor(acc, 16, 64);
    acc += __shfl_xor(acc, 32, 64);
    if (lane < 16) agg16[wid * 16 + k] = acc + g[wid * 16 + k];
}

// h2 = relu(dinv*(agg16@W2) + b2); c = h2 . fcW; pool[batch[i]] += c
__global__ void k_fin(const float* __restrict__ agg16, const float* __restrict__ dinv,
                      const float* __restrict__ W2, const float* __restrict__ b2,
                      const float* __restrict__ fcW, const int* __restrict__ batch,
                      float* __restrict__ pool, int* __restrict__ gcnt, int N) {
    __shared__ float sW[512], sb[32], sf[32];
    for (int t = threadIdx.x; t < 512; t += blockDim.x) sW[t] = W2[t];
    if (threadIdx.x < 32) {
        sb[threadIdx.x] = b2[threadIdx.x];
        sf[threadIdx.x] = fcW[threadIdx.x];
    }
    __syncthreads();
    int i = blockIdx.x * blockDim.x + threadIdx.x;
    if (i >= N) return;
    float di = dinv[i];
    float a[16];
    const float4* a4 = (const float4*)(agg16 + i * 16);
#pragma unroll
    for (int q = 0; q < 4; ++q) {
        float4 v = a4[q];
        a[q * 4 + 0] = v.x; a[q * 4 + 1] = v.y; a[q * 4 + 2] = v.z; a[q * 4 + 3] = v.w;
    }
    float c = 0.f;
#pragma unroll
    for (int jj = 0; jj < 32; ++jj) {
        float acc = 0.f;
#pragma unroll
        for (int kk = 0; kk < 16; ++kk) acc = fmaf(a[kk], sW[kk * 32 + jj], acc);
        float h = fmaxf(fmaf(di, acc, sb[jj]), 0.f);
        c = fmaf(h, sf[jj], c);
    }
    int b = batch[i];
    atomicAdd(&pool[b], c);
    atomicAdd(&gcnt[b], 1);
}

__global__ void k_out(const float* __restrict__ pool, const int* __restrict__ gcnt,
                      const float* __restrict__ fcb, float* __restrict__ out, int G) {
    int gI = blockIdx.x * blockDim.x + threadIdx.x;
    if (gI < G) out[gI] = pool[gI] / fmaxf((float)gcnt[gI], 1.f) + fcb[0];
}

extern "C" void kernel_launch(void* const* d_in, const int* in_sizes, int n_in,
                              void* d_out, int out_size, void* d_ws, size_t ws_size,
                              hipStream_t stream) {
    const float* x    = (const float*)d_in[0];
    const int*   ei   = (const int*)d_in[1];
    const int*   batch= (const int*)d_in[2];
    const float* W1   = (const float*)d_in[3];
    const float* b1   = (const float*)d_in[4];
    const float* W2   = (const float*)d_in[5];
    const float* b2   = (const float*)d_in[6];
    const float* fcW  = (const float*)d_in[7];
    const float* fcb  = (const float*)d_in[8];
    float* out = (float*)d_out;

    const int N = in_sizes[0] / 5;
    const int E = in_sizes[1] / 2;
    const int G = out_size;  // 1024

    const int* src = ei;
    const int* dst = ei + E;

    // workspace carve (N multiple of 16 -> all offsets 16B-aligned)
    char* ws = (char*)d_ws;
    int*   deg    = (int*)  (ws);                              // N
    int*   rowptr = (int*)  (ws + (size_t)4 * N);              // N+1
    int*   cursor = (int*)  (ws + (size_t)8 * N + 16);         // N
    float* dinv   = (float*)(ws + (size_t)12 * N + 16);        // N
    float* sx8    = (float*)(ws + (size_t)16 * N + 16);        // 8N
    float* agg8   = (float*)(ws + (size_t)48 * N + 16);        // 8N
    float* g      = (float*)(ws + (size_t)80 * N + 16);        // 16N
    float* agg16  = (float*)(ws + (size_t)144 * N + 16);       // 16N
    int*   ecsr   = (int*)  (ws + (size_t)208 * N + 16);       // E
    float* pool   = (float*)(ws + (size_t)208 * N + 16 + (size_t)4 * E); // G
    int*   gcnt   = (int*)  (ws + (size_t)208 * N + 16 + (size_t)4 * E + (size_t)4 * G); // G

    hipMemsetAsync(deg, 0, (size_t)4 * N, stream);
    hipMemsetAsync(pool, 0, (size_t)8 * G, stream);  // pool + gcnt contiguous

    k_degree<<<(E + BLK - 1) / BLK, BLK, 0, stream>>>(dst, E, deg);
    k_prep<<<(N + BLK - 1) / BLK, BLK, 0, stream>>>(x, deg, dinv, sx8, N);
    k_scan<<<1, 1024, 0, stream>>>(deg, rowptr, cursor, N);
    k_fill<<<(E + BLK - 1) / BLK, BLK, 0, stream>>>(src, dst, cursor, ecsr, E);
    {
        int blocks = (N * 64 + BLK - 1) / BLK;
        k_gather8<<<blocks, BLK, 0, stream>>>(rowptr, ecsr, sx8, agg8, N);
    }
    k_lin1<<<(N + BLK - 1) / BLK, BLK, 0, stream>>>(agg8, dinv, W1, b1, g, N);
    {
        int blocks = (N * 64 + BLK - 1) / BLK;
        k_gather16<<<blocks, BLK, 0, stream>>>(rowptr, ecsr, g, agg16, N);
    }
    k_fin<<<(N + BLK - 1) / BLK, BLK, 0, stream>>>(agg16, dinv, W2, b2, fcW, batch, pool, gcnt, N);
    k_out<<<(G + BLK - 1) / BLK, BLK, 0, stream>>>(pool, gcnt, fcb, out, G);
}

// Round 4
// 508.429 us; speedup vs baseline: 1.6336x; 1.6336x over previous
//
#include <hip/hip_runtime.h>

// GCN: 2x GCNConv (5->16->32) + global mean pool + linear head.
// v4: destination-binned aggregation. Edges are binned into NB dst-range
// buckets as packed 4B records; each aggregation pass accumulates into an
// LDS tile per bucket (gathers from a cache-resident table), then flushes
// with coalesced atomics. No random-line RMW traffic anywhere.
// Aggregation done in each layer's INPUT dim (5(pad8), then 16); @W applied
// after. Self-loops folded into accumulator init; symmetric norm folded into
// pre-scale (dinv[src]) and post-scale (dinv[dst]).

#define NB 128            // buckets
#define RANGE 784         // nodes per bucket; NB*RANGE = 100352 >= N
#define NBR (NB * RANGE)
#define K8 4              // blocks per bucket, layer-1 pass
#define K16 4             // blocks per bucket, layer-2 pass
#define KD 4              // blocks per bucket, degree pass
#define BINCHUNK 4096
#define PSPREAD 8

__global__ void k_hist(const int* __restrict__ dst, int E, int* __restrict__ bhist) {
    __shared__ int h[NB];
    for (int t = threadIdx.x; t < NB; t += blockDim.x) h[t] = 0;
    __syncthreads();
    for (int e = blockIdx.x * blockDim.x + threadIdx.x; e < E; e += gridDim.x * blockDim.x)
        atomicAdd(&h[dst[e] / RANGE], 1);
    __syncthreads();
    for (int t = threadIdx.x; t < NB; t += blockDim.x)
        if (h[t]) atomicAdd(&bhist[t], h[t]);
}

__global__ void k_scan(const int* __restrict__ bhist, int* __restrict__ bbase,
                       int* __restrict__ bcursor) {
    __shared__ int s[NB];
    int t = threadIdx.x;  // 128 threads
    int v = bhist[t];
    s[t] = v;
    __syncthreads();
    for (int off = 1; off < NB; off <<= 1) {
        int u = (t >= off) ? s[t - off] : 0;
        __syncthreads();
        s[t] += u;
        __syncthreads();
    }
    bbase[t] = s[t] - v;
    bcursor[t] = s[t] - v;
    if (t == NB - 1) bbase[NB] = s[t];
}

// bin edges into bucket-contiguous recbuf; rec = (src<<10) | dst_local
__global__ void k_bin(const int* __restrict__ src, const int* __restrict__ dst,
                      int* __restrict__ bcursor, unsigned int* __restrict__ recbuf, int E) {
    __shared__ int h[NB], h2[NB], base_l[NB];
    for (int t = threadIdx.x; t < NB; t += blockDim.x) { h[t] = 0; h2[t] = 0; }
    __syncthreads();
    int e0 = blockIdx.x * BINCHUNK;
    int e1 = min(e0 + BINCHUNK, E);
    for (int e = e0 + threadIdx.x; e < e1; e += blockDim.x)
        atomicAdd(&h[dst[e] / RANGE], 1);
    __syncthreads();
    for (int t = threadIdx.x; t < NB; t += blockDim.x)
        base_l[t] = h[t] ? atomicAdd(&bcursor[t], h[t]) : 0;
    __syncthreads();
    for (int e = e0 + threadIdx.x; e < e1; e += blockDim.x) {
        int d = dst[e];
        int b = d / RANGE;
        int rank = atomicAdd(&h2[b], 1);
        recbuf[base_l[b] + rank] = ((unsigned)src[e] << 10) | (unsigned)(d - b * RANGE);
    }
}

// in-degree from binned records (LDS counting, coalesced flush)
__global__ void k_degbin(const int* __restrict__ bbase, const unsigned int* __restrict__ recbuf,
                         int* __restrict__ deg) {
    __shared__ int cnt[RANGE];
    int b = blockIdx.x / KD, k = blockIdx.x % KD;
    for (int t = threadIdx.x; t < RANGE; t += blockDim.x) cnt[t] = 0;
    __syncthreads();
    int s0 = bbase[b], len = bbase[b + 1] - s0;
    int rs = s0 + (int)((long long)len * k / KD);
    int re = s0 + (int)((long long)len * (k + 1) / KD);
    for (int r = rs + threadIdx.x; r < re; r += blockDim.x)
        atomicAdd(&cnt[recbuf[r] & 1023], 1);
    __syncthreads();
    for (int t = threadIdx.x; t < RANGE; t += blockDim.x)
        if (cnt[t]) atomicAdd(&deg[b * RANGE + t], cnt[t]);
}

// dinv = rsqrt(deg+1); sx8 = [dinv*x (5), 0,0,0]; agg8 init = sx8 (self-loop)
__global__ void k_prep(const float* __restrict__ x, const int* __restrict__ deg,
                       float* __restrict__ dinv, float* __restrict__ sx8,
                       float* __restrict__ agg8, int N) {
    int i = blockIdx.x * blockDim.x + threadIdx.x;
    if (i >= N) return;
    float di = rsqrtf((float)(deg[i] + 1));
    dinv[i] = di;
    float4 a, b;
    a.x = x[i * 5 + 0] * di; a.y = x[i * 5 + 1] * di;
    a.z = x[i * 5 + 2] * di; a.w = x[i * 5 + 3] * di;
    b.x = x[i * 5 + 4] * di; b.y = 0.f; b.z = 0.f; b.w = 0.f;
    float4* p = (float4*)(sx8 + i * 8);
    float4* q = (float4*)(agg8 + i * 8);
    p[0] = a; p[1] = b;
    q[0] = a; q[1] = b;
}

// layer-1 aggregation: LDS tile per bucket (stride 9 vs banks), 2 lanes/record
__global__ __launch_bounds__(512) void k_proc8(const int* __restrict__ bbase,
        const unsigned int* __restrict__ recbuf, const float* __restrict__ sx8,
        float* __restrict__ agg8) {
    __shared__ float acc[RANGE * 9];
    int b = blockIdx.x / K8, k = blockIdx.x % K8;
    for (int t = threadIdx.x; t < RANGE * 9; t += 512) acc[t] = 0.f;
    __syncthreads();
    int s0 = bbase[b], len = bbase[b + 1] - s0;
    int rs = s0 + (int)((long long)len * k / K8);
    int re = s0 + (int)((long long)len * (k + 1) / K8);
    int sub = threadIdx.x & 1;
    const int STR = 256;
    int r = rs + (threadIdx.x >> 1);
    for (; r + 3 * STR < re; r += 4 * STR) {
        unsigned q0 = recbuf[r], q1 = recbuf[r + STR], q2 = recbuf[r + 2 * STR], q3 = recbuf[r + 3 * STR];
        float4 v0 = *(const float4*)(sx8 + (size_t)(q0 >> 10) * 8 + sub * 4);
        float4 v1 = *(const float4*)(sx8 + (size_t)(q1 >> 10) * 8 + sub * 4);
        float4 v2 = *(const float4*)(sx8 + (size_t)(q2 >> 10) * 8 + sub * 4);
        float4 v3 = *(const float4*)(sx8 + (size_t)(q3 >> 10) * 8 + sub * 4);
        float* a0 = acc + (q0 & 1023) * 9 + sub * 4;
        float* a1 = acc + (q1 & 1023) * 9 + sub * 4;
        float* a2 = acc + (q2 & 1023) * 9 + sub * 4;
        float* a3 = acc + (q3 & 1023) * 9 + sub * 4;
        atomicAdd(a0 + 0, v0.x); atomicAdd(a0 + 1, v0.y); atomicAdd(a0 + 2, v0.z); atomicAdd(a0 + 3, v0.w);
        atomicAdd(a1 + 0, v1.x); atomicAdd(a1 + 1, v1.y); atomicAdd(a1 + 2, v1.z); atomicAdd(a1 + 3, v1.w);
        atomicAdd(a2 + 0, v2.x); atomicAdd(a2 + 1, v2.y); atomicAdd(a2 + 2, v2.z); atomicAdd(a2 + 3, v2.w);
        atomicAdd(a3 + 0, v3.x); atomicAdd(a3 + 1, v3.y); atomicAdd(a3 + 2, v3.z); atomicAdd(a3 + 3, v3.w);
    }
    for (; r < re; r += STR) {
        unsigned q0 = recbuf[r];
        float4 v0 = *(const float4*)(sx8 + (size_t)(q0 >> 10) * 8 + sub * 4);
        float* a0 = acc + (q0 & 1023) * 9 + sub * 4;
        atomicAdd(a0 + 0, v0.x); atomicAdd(a0 + 1, v0.y); atomicAdd(a0 + 2, v0.z); atomicAdd(a0 + 3, v0.w);
    }
    __syncthreads();
    float* out = agg8 + (size_t)b * RANGE * 8;
    for (int t = threadIdx.x; t < RANGE * 8; t += 512) {
        float v = acc[(t >> 3) * 9 + (t & 7)];
        if (v != 0.f) atomicAdd(&out[t], v);  // coalesced lines
    }
}

// h1 = relu(dinv*(agg8[:5]@W1) + b1); g = dinv*h1; agg16 init = g (self-loop)
__global__ void k_lin1(const float* __restrict__ agg8, const float* __restrict__ dinv,
                       const float* __restrict__ W1, const float* __restrict__ b1,
                       float* __restrict__ g, float* __restrict__ agg16, int N) {
    __shared__ float sW[80], sb[16];
    if (threadIdx.x < 80) sW[threadIdx.x] = W1[threadIdx.x];
    if (threadIdx.x < 16) sb[threadIdx.x] = b1[threadIdx.x];
    __syncthreads();
    int i = blockIdx.x * blockDim.x + threadIdx.x;
    if (i >= N) return;
    float di = dinv[i];
    const float4* a4 = (const float4*)(agg8 + (size_t)i * 8);
    float4 v0 = a4[0], v1 = a4[1];
    float a[5] = {v0.x, v0.y, v0.z, v0.w, v1.x};
    float4* g4 = (float4*)(g + (size_t)i * 16);
    float4* q4 = (float4*)(agg16 + (size_t)i * 16);
#pragma unroll
    for (int q = 0; q < 4; ++q) {
        float4 v;
        float* vp = (float*)&v;
#pragma unroll
        for (int r = 0; r < 4; ++r) {
            int kk = q * 4 + r;
            float h = 0.f;
#pragma unroll
            for (int d = 0; d < 5; ++d) h = fmaf(a[d], sW[d * 16 + kk], h);
            h = fmaxf(fmaf(di, h, sb[kk]), 0.f);
            vp[r] = h * di;
        }
        g4[q] = v;
        q4[q] = v;
    }
}

// layer-2 aggregation: LDS tile (stride 17), 4 lanes/record
__global__ __launch_bounds__(512) void k_proc16(const int* __restrict__ bbase,
        const unsigned int* __restrict__ recbuf, const float* __restrict__ g,
        float* __restrict__ agg16) {
    __shared__ float acc[RANGE * 17];
    int b = blockIdx.x / K16, k = blockIdx.x % K16;
    for (int t = threadIdx.x; t < RANGE * 17; t += 512) acc[t] = 0.f;
    __syncthreads();
    int s0 = bbase[b], len = bbase[b + 1] - s0;
    int rs = s0 + (int)((long long)len * k / K16);
    int re = s0 + (int)((long long)len * (k + 1) / K16);
    int sub = threadIdx.x & 3;
    const int STR = 128;
    int r = rs + (threadIdx.x >> 2);
    for (; r + 3 * STR < re; r += 4 * STR) {
        unsigned q0 = recbuf[r], q1 = recbuf[r + STR], q2 = recbuf[r + 2 * STR], q3 = recbuf[r + 3 * STR];
        float4 v0 = *(const float4*)(g + (size_t)(q0 >> 10) * 16 + sub * 4);
        float4 v1 = *(const float4*)(g + (size_t)(q1 >> 10) * 16 + sub * 4);
        float4 v2 = *(const float4*)(g + (size_t)(q2 >> 10) * 16 + sub * 4);
        float4 v3 = *(const float4*)(g + (size_t)(q3 >> 10) * 16 + sub * 4);
        float* a0 = acc + (q0 & 1023) * 17 + sub * 4;
        float* a1 = acc + (q1 & 1023) * 17 + sub * 4;
        float* a2 = acc + (q2 & 1023) * 17 + sub * 4;
        float* a3 = acc + (q3 & 1023) * 17 + sub * 4;
        atomicAdd(a0 + 0, v0.x); atomicAdd(a0 + 1, v0.y); atomicAdd(a0 + 2, v0.z); atomicAdd(a0 + 3, v0.w);
        atomicAdd(a1 + 0, v1.x); atomicAdd(a1 + 1, v1.y); atomicAdd(a1 + 2, v1.z); atomicAdd(a1 + 3, v1.w);
        atomicAdd(a2 + 0, v2.x); atomicAdd(a2 + 1, v2.y); atomicAdd(a2 + 2, v2.z); atomicAdd(a2 + 3, v2.w);
        atomicAdd(a3 + 0, v3.x); atomicAdd(a3 + 1, v3.y); atomicAdd(a3 + 2, v3.z); atomicAdd(a3 + 3, v3.w);
    }
    for (; r < re; r += STR) {
        unsigned q0 = recbuf[r];
        float4 v0 = *(const float4*)(g + (size_t)(q0 >> 10) * 16 + sub * 4);
        float* a0 = acc + (q0 & 1023) * 17 + sub * 4;
        atomicAdd(a0 + 0, v0.x); atomicAdd(a0 + 1, v0.y); atomicAdd(a0 + 2, v0.z); atomicAdd(a0 + 3, v0.w);
    }
    __syncthreads();
    float* out = agg16 + (size_t)b * RANGE * 16;
    for (int t = threadIdx.x; t < RANGE * 16; t += 512) {
        float v = acc[(t >> 4) * 17 + (t & 15)];
        if (v != 0.f) atomicAdd(&out[t], v);
    }
}

// h2 = relu(dinv*(agg16@W2) + b2); c = h2 . fcW; spread-8 pool atomics
__global__ void k_fin(const float* __restrict__ agg16, const float* __restrict__ dinv,
                      const float* __restrict__ W2, const float* __restrict__ b2,
                      const float* __restrict__ fcW, const int* __restrict__ batch,
                      float* __restrict__ pool, int* __restrict__ gcnt, int N, int G) {
    __shared__ float sW[512], sb[32], sf[32];
    for (int t = threadIdx.x; t < 512; t += blockDim.x) sW[t] = W2[t];
    if (threadIdx.x < 32) {
        sb[threadIdx.x] = b2[threadIdx.x];
        sf[threadIdx.x] = fcW[threadIdx.x];
    }
    __syncthreads();
    int i = blockIdx.x * blockDim.x + threadIdx.x;
    if (i >= N) return;
    float di = dinv[i];
    float a[16];
    const float4* a4 = (const float4*)(agg16 + (size_t)i * 16);
#pragma unroll
    for (int q = 0; q < 4; ++q) {
        float4 v = a4[q];
        a[q * 4 + 0] = v.x; a[q * 4 + 1] = v.y; a[q * 4 + 2] = v.z; a[q * 4 + 3] = v.w;
    }
    float c = 0.f;
#pragma unroll
    for (int jj = 0; jj < 32; ++jj) {
        float acc2 = 0.f;
#pragma unroll
        for (int kk = 0; kk < 16; ++kk) acc2 = fmaf(a[kk], sW[kk * 32 + jj], acc2);
        float h = fmaxf(fmaf(di, acc2, sb[jj]), 0.f);
        c = fmaf(h, sf[jj], c);
    }
    int bidx = batch[i];
    int slot = i & (PSPREAD - 1);
    atomicAdd(&pool[slot * G + bidx], c);
    atomicAdd(&gcnt[slot * G + bidx], 1);
}

__global__ void k_out(const float* __restrict__ pool, const int* __restrict__ gcnt,
                      const float* __restrict__ fcb, float* __restrict__ out, int G) {
    int gI = blockIdx.x * blockDim.x + threadIdx.x;
    if (gI >= G) return;
    float s = 0.f; int c = 0;
#pragma unroll
    for (int k = 0; k < PSPREAD; ++k) { s += pool[k * G + gI]; c += gcnt[k * G + gI]; }
    out[gI] = s / fmaxf((float)c, 1.f) + fcb[0];
}

extern "C" void kernel_launch(void* const* d_in, const int* in_sizes, int n_in,
                              void* d_out, int out_size, void* d_ws, size_t ws_size,
                              hipStream_t stream) {
    const float* x    = (const float*)d_in[0];
    const int*   ei   = (const int*)d_in[1];
    const int*   batch= (const int*)d_in[2];
    const float* W1   = (const float*)d_in[3];
    const float* b1   = (const float*)d_in[4];
    const float* W2   = (const float*)d_in[5];
    const float* b2   = (const float*)d_in[6];
    const float* fcW  = (const float*)d_in[7];
    const float* fcb  = (const float*)d_in[8];
    float* out = (float*)d_out;

    const int N = in_sizes[0] / 5;
    const int E = in_sizes[1] / 2;
    const int G = out_size;  // 1024

    const int* src = ei;
    const int* dst = ei + E;

    // workspace carve (all offsets 16B-aligned)
    char* ws = (char*)d_ws;
    size_t o = 0;
    int*   deg    = (int*)  (ws + o); o += (size_t)4 * NBR;        // 401,408
    float* dinv   = (float*)(ws + o); o += (size_t)4 * NBR;
    float* sx8    = (float*)(ws + o); o += (size_t)32 * N;
    float* agg8   = (float*)(ws + o); o += (size_t)32 * NBR;
    float* g      = (float*)(ws + o); o += (size_t)64 * N;
    float* agg16  = (float*)(ws + o); o += (size_t)64 * NBR;
    unsigned int* recbuf = (unsigned int*)(ws + o); o += (size_t)4 * E;
    int*   bhist  = (int*)  (ws + o); o += 1024;
    int*   bbase  = (int*)  (ws + o); o += 1024;   // NB+1 ints
    int*   bcursor= (int*)  (ws + o); o += 1024;
    float* pool   = (float*)(ws + o); o += (size_t)4 * PSPREAD * G;
    int*   gcnt   = (int*)  (ws + o); o += (size_t)4 * PSPREAD * G;

    hipMemsetAsync(deg, 0, (size_t)4 * NBR, stream);
    hipMemsetAsync(bhist, 0, 1024, stream);
    hipMemsetAsync(pool, 0, (size_t)8 * PSPREAD * G, stream);  // pool+gcnt contiguous

    k_hist<<<256, 256, 0, stream>>>(dst, E, bhist);
    k_scan<<<1, NB, 0, stream>>>(bhist, bbase, bcursor);
    k_bin<<<(E + BINCHUNK - 1) / BINCHUNK, 256, 0, stream>>>(src, dst, bcursor, recbuf, E);
    k_degbin<<<NB * KD, 256, 0, stream>>>(bbase, recbuf, deg);
    k_prep<<<(N + 255) / 256, 256, 0, stream>>>(x, deg, dinv, sx8, agg8, N);
    k_proc8<<<NB * K8, 512, 0, stream>>>(bbase, recbuf, sx8, agg8);
    k_lin1<<<(N + 255) / 256, 256, 0, stream>>>(agg8, dinv, W1, b1, g, agg16, N);
    k_proc16<<<NB * K16, 512, 0, stream>>>(bbase, recbuf, g, agg16);
    k_fin<<<(N + 255) / 256, 256, 0, stream>>>(agg16, dinv, W2, b2, fcW, batch, pool, gcnt, N, G);
    k_out<<<(G + 255) / 256, 256, 0, stream>>>(pool, gcnt, fcb, out, G);
}

// Round 6
// 228.022 us; speedup vs baseline: 3.6425x; 2.2297x over previous
//
#include <hip/hip_runtime.h>

// GCN: 2x GCNConv (5->16->32) + global mean pool + linear head.
// v5b: two-level CSR build (bucket binning + per-bucket LDS counting sort),
// then atomic-free gather-reduce aggregations (register accumulation).
// Fix vs v5: k_sort's lbase/rowptr writeout now covers all RANGE entries
// (was guarded by t<RANGE with only 512 threads -> uninit lbase -> OOB).

#define NB 128            // dst buckets
#define RANGE 784         // nodes per bucket; NB*RANGE = 100352 >= N
#define NBR (NB * RANGE)
#define BINCHUNK 4096
#define PSPREAD 8

__global__ void k_hist(const int* __restrict__ dst, int E, int* __restrict__ bhist) {
    __shared__ int h[NB];
    for (int t = threadIdx.x; t < NB; t += blockDim.x) h[t] = 0;
    __syncthreads();
    for (int e = blockIdx.x * blockDim.x + threadIdx.x; e < E; e += gridDim.x * blockDim.x)
        atomicAdd(&h[dst[e] / RANGE], 1);
    __syncthreads();
    for (int t = threadIdx.x; t < NB; t += blockDim.x)
        if (h[t]) atomicAdd(&bhist[t], h[t]);
}

__global__ void k_scan(const int* __restrict__ bhist, int* __restrict__ bbase,
                       int* __restrict__ bcursor) {
    __shared__ int s[NB];
    int t = threadIdx.x;  // NB threads
    int v = bhist[t];
    s[t] = v;
    __syncthreads();
    for (int off = 1; off < NB; off <<= 1) {
        int u = (t >= off) ? s[t - off] : 0;
        __syncthreads();
        s[t] += u;
        __syncthreads();
    }
    bbase[t] = s[t] - v;
    bcursor[t] = s[t] - v;
    if (t == NB - 1) bbase[NB] = s[t];
}

// bin edges into bucket-contiguous recbuf; rec = (src<<10) | dst_local
__global__ void k_bin(const int* __restrict__ src, const int* __restrict__ dst,
                      int* __restrict__ bcursor, unsigned int* __restrict__ recbuf, int E) {
    __shared__ int h[NB], h2[NB], base_l[NB];
    for (int t = threadIdx.x; t < NB; t += blockDim.x) { h[t] = 0; h2[t] = 0; }
    __syncthreads();
    int e0 = blockIdx.x * BINCHUNK;
    int e1 = min(e0 + BINCHUNK, E);
    for (int e = e0 + threadIdx.x; e < e1; e += blockDim.x)
        atomicAdd(&h[dst[e] / RANGE], 1);
    __syncthreads();
    for (int t = threadIdx.x; t < NB; t += blockDim.x)
        base_l[t] = h[t] ? atomicAdd(&bcursor[t], h[t]) : 0;
    __syncthreads();
    for (int e = e0 + threadIdx.x; e < e1; e += blockDim.x) {
        int d = dst[e];
        int b = d / RANGE;
        int rank = atomicAdd(&h2[b], 1);
        recbuf[base_l[b] + rank] = ((unsigned)src[e] << 10) | (unsigned)(d - b * RANGE);
    }
}

// per-bucket LDS counting sort: recbuf -> srt (src ids grouped by dst), rowptr
__global__ __launch_bounds__(512) void k_sort(const int* __restrict__ bbase,
        const unsigned int* __restrict__ recbuf, int* __restrict__ rowptr,
        int* __restrict__ srt) {
    __shared__ int cnt[RANGE], lbase[RANGE], rank[RANGE];
    __shared__ int sc[1024];
    int b = blockIdx.x;
    int t = threadIdx.x;
    for (int i = t; i < RANGE; i += 512) { cnt[i] = 0; rank[i] = 0; }
    __syncthreads();
    int s0 = bbase[b], s1 = bbase[b + 1];
    for (int r = s0 + t; r < s1; r += 512)
        atomicAdd(&cnt[recbuf[r] & 1023], 1);
    __syncthreads();
    sc[t] = (t < RANGE) ? cnt[t] : 0;
    sc[t + 512] = (t + 512 < RANGE) ? cnt[t + 512] : 0;
    __syncthreads();
    for (int off = 1; off < 1024; off <<= 1) {
        int a0 = (t >= off) ? sc[t - off] : 0;
        int i2 = t + 512;
        int a1 = (i2 >= off) ? sc[i2 - off] : 0;
        __syncthreads();
        sc[t] += a0; sc[i2] += a1;
        __syncthreads();
    }
    for (int i = t; i < RANGE; i += 512) {
        lbase[i] = sc[i] - cnt[i];
        rowptr[b * RANGE + i] = s0 + lbase[i];
    }
    if (b == NB - 1 && t == 0) rowptr[NBR] = s1;
    __syncthreads();
    for (int r = s0 + t; r < s1; r += 512) {
        unsigned rec = recbuf[r];
        int dl = rec & 1023;
        int pos = s0 + lbase[dl] + atomicAdd(&rank[dl], 1);
        srt[pos] = (int)(rec >> 10);
    }
}

// dinv = rsqrt(deg+1) from rowptr; sx8 = [dinv*x (5), 0,0,0]
__global__ void k_prep(const float* __restrict__ x, const int* __restrict__ rowptr,
                       float* __restrict__ dinv, float* __restrict__ sx8, int N) {
    int i = blockIdx.x * blockDim.x + threadIdx.x;
    if (i >= N) return;
    int deg = rowptr[i + 1] - rowptr[i];
    float di = rsqrtf((float)(deg + 1));
    dinv[i] = di;
    float4 a, b;
    a.x = x[i * 5 + 0] * di; a.y = x[i * 5 + 1] * di;
    a.z = x[i * 5 + 2] * di; a.w = x[i * 5 + 3] * di;
    b.x = x[i * 5 + 4] * di; b.y = 0.f; b.z = 0.f; b.w = 0.f;
    float4* p = (float4*)(sx8 + (size_t)i * 8);
    p[0] = a; p[1] = b;
}

// one wave per node; 8 feature lanes x 8 row slots; register accumulation
__global__ void k_gather8(const int* __restrict__ rowptr, const int* __restrict__ srt,
                          const float* __restrict__ sx8, float* __restrict__ agg8, int N) {
    int wid = (blockIdx.x * blockDim.x + threadIdx.x) >> 6;
    int lane = threadIdx.x & 63;
    if (wid >= N) return;
    int k = lane & 7, j = lane >> 3;
    int p0 = rowptr[wid], p1 = rowptr[wid + 1];
    float acc = 0.f;
    int p = p0 + j;
    for (; p + 8 < p1; p += 16) {
        int sA = srt[p], sB = srt[p + 8];
        float vA = sx8[(size_t)sA * 8 + k];
        float vB = sx8[(size_t)sB * 8 + k];
        acc += vA + vB;
    }
    for (; p < p1; p += 8) acc += sx8[(size_t)srt[p] * 8 + k];
    acc += __shfl_xor(acc, 8, 64);
    acc += __shfl_xor(acc, 16, 64);
    acc += __shfl_xor(acc, 32, 64);
    if (lane < 8) agg8[(size_t)wid * 8 + k] = acc + sx8[(size_t)wid * 8 + k];
}

// h1 = relu(dinv*(agg8[:5]@W1) + b1); g = dinv*h1 (16)
__global__ void k_lin1(const float* __restrict__ agg8, const float* __restrict__ dinv,
                       const float* __restrict__ W1, const float* __restrict__ b1,
                       float* __restrict__ g, int N) {
    __shared__ float sW[80], sb[16];
    if (threadIdx.x < 80) sW[threadIdx.x] = W1[threadIdx.x];
    if (threadIdx.x < 16) sb[threadIdx.x] = b1[threadIdx.x];
    __syncthreads();
    int i = blockIdx.x * blockDim.x + threadIdx.x;
    if (i >= N) return;
    float di = dinv[i];
    const float4* a4 = (const float4*)(agg8 + (size_t)i * 8);
    float4 v0 = a4[0], v1 = a4[1];
    float a[5] = {v0.x, v0.y, v0.z, v0.w, v1.x};
    float4* g4 = (float4*)(g + (size_t)i * 16);
#pragma unroll
    for (int q = 0; q < 4; ++q) {
        float4 v;
        float* vp = (float*)&v;
#pragma unroll
        for (int r = 0; r < 4; ++r) {
            int kk = q * 4 + r;
            float h = 0.f;
#pragma unroll
            for (int d = 0; d < 5; ++d) h = fmaf(a[d], sW[d * 16 + kk], h);
            h = fmaxf(fmaf(di, h, sb[kk]), 0.f);
            vp[r] = h * di;
        }
        g4[q] = v;
    }
}

// one wave per node; 16 feature lanes x 4 row slots; register accumulation
__global__ void k_gather16(const int* __restrict__ rowptr, const int* __restrict__ srt,
                           const float* __restrict__ g, float* __restrict__ agg16, int N) {
    int wid = (blockIdx.x * blockDim.x + threadIdx.x) >> 6;
    int lane = threadIdx.x & 63;
    if (wid >= N) return;
    int k = lane & 15, j = lane >> 4;
    int p0 = rowptr[wid], p1 = rowptr[wid + 1];
    float acc = 0.f;
    int p = p0 + j;
    for (; p + 12 < p1; p += 16) {
        int sA = srt[p], sB = srt[p + 4], sC = srt[p + 8], sD = srt[p + 12];
        float vA = g[(size_t)sA * 16 + k];
        float vB = g[(size_t)sB * 16 + k];
        float vC = g[(size_t)sC * 16 + k];
        float vD = g[(size_t)sD * 16 + k];
        acc += (vA + vB) + (vC + vD);
    }
    for (; p < p1; p += 4) acc += g[(size_t)srt[p] * 16 + k];
    acc += __shfl_xor(acc, 16, 64);
    acc += __shfl_xor(acc, 32, 64);
    if (lane < 16) agg16[(size_t)wid * 16 + k] = acc + g[(size_t)wid * 16 + k];
}

// h2 = relu(dinv*(agg16@W2) + b2); c = h2 . fcW; spread-8 pool atomics
__global__ void k_fin(const float* __restrict__ agg16, const float* __restrict__ dinv,
                      const float* __restrict__ W2, const float* __restrict__ b2,
                      const float* __restrict__ fcW, const int* __restrict__ batch,
                      float* __restrict__ pool, int* __restrict__ gcnt, int N, int G) {
    __shared__ float sW[512], sb[32], sf[32];
    for (int t = threadIdx.x; t < 512; t += blockDim.x) sW[t] = W2[t];
    if (threadIdx.x < 32) {
        sb[threadIdx.x] = b2[threadIdx.x];
        sf[threadIdx.x] = fcW[threadIdx.x];
    }
    __syncthreads();
    int i = blockIdx.x * blockDim.x + threadIdx.x;
    if (i >= N) return;
    float di = dinv[i];
    float a[16];
    const float4* a4 = (const float4*)(agg16 + (size_t)i * 16);
#pragma unroll
    for (int q = 0; q < 4; ++q) {
        float4 v = a4[q];
        a[q * 4 + 0] = v.x; a[q * 4 + 1] = v.y; a[q * 4 + 2] = v.z; a[q * 4 + 3] = v.w;
    }
    float c = 0.f;
#pragma unroll
    for (int jj = 0; jj < 32; ++jj) {
        float acc2 = 0.f;
#pragma unroll
        for (int kk = 0; kk < 16; ++kk) acc2 = fmaf(a[kk], sW[kk * 32 + jj], acc2);
        float h = fmaxf(fmaf(di, acc2, sb[jj]), 0.f);
        c = fmaf(h, sf[jj], c);
    }
    int bidx = batch[i];
    int slot = i & (PSPREAD - 1);
    atomicAdd(&pool[slot * G + bidx], c);
    atomicAdd(&gcnt[slot * G + bidx], 1);
}

__global__ void k_out(const float* __restrict__ pool, const int* __restrict__ gcnt,
                      const float* __restrict__ fcb, float* __restrict__ out, int G) {
    int gI = blockIdx.x * blockDim.x + threadIdx.x;
    if (gI >= G) return;
    float s = 0.f; int c = 0;
#pragma unroll
    for (int k = 0; k < PSPREAD; ++k) { s += pool[k * G + gI]; c += gcnt[k * G + gI]; }
    out[gI] = s / fmaxf((float)c, 1.f) + fcb[0];
}

extern "C" void kernel_launch(void* const* d_in, const int* in_sizes, int n_in,
                              void* d_out, int out_size, void* d_ws, size_t ws_size,
                              hipStream_t stream) {
    const float* x    = (const float*)d_in[0];
    const int*   ei   = (const int*)d_in[1];
    const int*   batch= (const int*)d_in[2];
    const float* W1   = (const float*)d_in[3];
    const float* b1   = (const float*)d_in[4];
    const float* W2   = (const float*)d_in[5];
    const float* b2   = (const float*)d_in[6];
    const float* fcW  = (const float*)d_in[7];
    const float* fcb  = (const float*)d_in[8];
    float* out = (float*)d_out;

    const int N = in_sizes[0] / 5;
    const int E = in_sizes[1] / 2;
    const int G = out_size;  // 1024

    const int* src = ei;
    const int* dst = ei + E;

    // workspace carve (all offsets 16B-aligned)
    char* ws = (char*)d_ws;
    size_t o = 0;
    int*   bhist  = (int*)  (ws + o); o += 1024;
    int*   bbase  = (int*)  (ws + o); o += 1024;            // NB+1 ints
    int*   bcursor= (int*)  (ws + o); o += 1024;
    int*   rowptr = (int*)  (ws + o); o += (size_t)4 * (NBR + 4);
    float* dinv   = (float*)(ws + o); o += (size_t)4 * N;
    float* sx8    = (float*)(ws + o); o += (size_t)32 * N;
    float* agg8   = (float*)(ws + o); o += (size_t)32 * N;
    float* agg16  = (float*)(ws + o); o += (size_t)64 * N;
    int*   srt    = (int*)  (ws + o); o += (size_t)4 * E;
    unsigned int* recbuf = (unsigned int*)(ws + o);         // 4E, dead after k_sort
    float* g      = (float*)(ws + o); o += (size_t)4 * E;   // g (64N) aliases recbuf
    float* pool   = (float*)(ws + o); o += (size_t)4 * PSPREAD * G;
    int*   gcnt   = (int*)  (ws + o); o += (size_t)4 * PSPREAD * G;

    hipMemsetAsync(bhist, 0, 1024, stream);
    hipMemsetAsync(pool, 0, (size_t)8 * PSPREAD * G, stream);  // pool+gcnt contiguous

    k_hist<<<256, 256, 0, stream>>>(dst, E, bhist);
    k_scan<<<1, NB, 0, stream>>>(bhist, bbase, bcursor);
    k_bin<<<(E + BINCHUNK - 1) / BINCHUNK, 256, 0, stream>>>(src, dst, bcursor, recbuf, E);
    k_sort<<<NB, 512, 0, stream>>>(bbase, recbuf, rowptr, srt);
    k_prep<<<(N + 255) / 256, 256, 0, stream>>>(x, rowptr, dinv, sx8, N);
    {
        int blocks = (int)(((long long)N * 64 + 255) / 256);
        k_gather8<<<blocks, 256, 0, stream>>>(rowptr, srt, sx8, agg8, N);
    }
    k_lin1<<<(N + 255) / 256, 256, 0, stream>>>(agg8, dinv, W1, b1, g, N);
    {
        int blocks = (int)(((long long)N * 64 + 255) / 256);
        k_gather16<<<blocks, 256, 0, stream>>>(rowptr, srt, g, agg16, N);
    }
    k_fin<<<(N + 255) / 256, 256, 0, stream>>>(agg16, dinv, W2, b2, fcW, batch, pool, gcnt, N, G);
    k_out<<<(G + 255) / 256, 256, 0, stream>>>(pool, gcnt, fcb, out, G);
}